// Round 9
// baseline (331.828 us; speedup 1.0000x reference)
//
#include <hip/hip_runtime.h>
#include <hip/hip_bf16.h>

#define S_LEN 2048
#define HID   2048
#define NH    32
#define NKV   8
#define HD    64
#define ROT   16
#define QKV_N 3072
#define ROWS  4096   // B*S

typedef __attribute__((ext_vector_type(8))) short short8;
typedef __attribute__((ext_vector_type(8))) unsigned short ushort8;
typedef __attribute__((ext_vector_type(4))) float floatx4;

static __device__ __forceinline__ float bf2f(ushort u) {
  union { unsigned int i; float f; } v; v.i = ((unsigned int)u) << 16; return v.f;
}
static __device__ __forceinline__ ushort f2bf(float f) {
  union { __hip_bfloat16 h; ushort u; } v; v.h = __float2bfloat16(f); return v.u;
}

// ---------------------------------------------------------------------------
// fp32 -> bf16 convert, 8 elems/thread (inputs are fp32)
// ---------------------------------------------------------------------------
__global__ __launch_bounds__(256)
void cvt_f32_bf16(const float* __restrict__ in, ushort* __restrict__ out, int n8) {
  const int i = blockIdx.x * 256 + threadIdx.x;
  if (i >= n8) return;
  const float4 a = ((const float4*)in)[2 * i];
  const float4 b = ((const float4*)in)[2 * i + 1];
  ushort8 o;
  o[0] = f2bf(a.x); o[1] = f2bf(a.y); o[2] = f2bf(a.z); o[3] = f2bf(a.w);
  o[4] = f2bf(b.x); o[5] = f2bf(b.y); o[6] = f2bf(b.z); o[7] = f2bf(b.w);
  ((ushort8*)out)[i] = o;
}

// ---------------------------------------------------------------------------
// NT GEMM (m97 structure): 128x128 tile, BK=32, global_load_lds width-16,
// 4 waves x 4x4 mfma_f32_16x16x32_bf16. OUT_BF16 ? bf16 C : fp32 C.
// + XCD-bijective block swizzle (T1); nwg%8==0 for both shapes (768, 512).
// ---------------------------------------------------------------------------
template<bool OUT_BF16>
__global__ __launch_bounds__(256, 2)
void gemm_nt(const ushort* __restrict__ A, const ushort* __restrict__ B,
             void* __restrict__ Cout, int M, int N, int K) {
  __shared__ ushort lA[128 * 32];
  __shared__ ushort lB[128 * 32];
  const int tid  = threadIdx.x;
  const int wave = tid >> 6, lane = tid & 63;
  const int wr = (wave >> 1) * 64, wc = (wave & 1) * 64;
  const int frow = lane & 15, quad = lane >> 4;
  const int fk = quad * 8;
  const int srow = lane >> 2, skk = (lane & 3) * 8;

  // XCD-bijective swizzle of the linear block id
  const int gx  = gridDim.x;
  const int nwg = gx * gridDim.y;
  const int lin = blockIdx.y * gx + blockIdx.x;
  const int cpx = nwg >> 3;
  const int swz = (lin & 7) * cpx + (lin >> 3);
  const int bxi = swz % gx, byi = swz / gx;

  const size_t bm = (size_t)byi * 128;
  const size_t bn = (size_t)bxi * 128;
  const ushort* Ab = A + bm * K;
  const ushort* Bb = B + bn * K;
  floatx4 acc[4][4] = {};

  for (int k0 = 0; k0 < K; k0 += 32) {
    __syncthreads();
    {
      const int c0 = wave * 2;
      const ushort* ga = Ab + (size_t)(c0 * 16 + srow) * K + (k0 + skk);
      const ushort* gb = Bb + (size_t)(c0 * 16 + srow) * K + (k0 + skk);
      __builtin_amdgcn_global_load_lds((const __attribute__((address_space(1))) void*)ga,
          (__attribute__((address_space(3))) void*)&lA[c0 * 512], 16, 0, 0);
      __builtin_amdgcn_global_load_lds((const __attribute__((address_space(1))) void*)gb,
          (__attribute__((address_space(3))) void*)&lB[c0 * 512], 16, 0, 0);
      __builtin_amdgcn_global_load_lds((const __attribute__((address_space(1))) void*)(ga + (size_t)16 * K),
          (__attribute__((address_space(3))) void*)&lA[(c0 + 1) * 512], 16, 0, 0);
      __builtin_amdgcn_global_load_lds((const __attribute__((address_space(1))) void*)(gb + (size_t)16 * K),
          (__attribute__((address_space(3))) void*)&lB[(c0 + 1) * 512], 16, 0, 0);
    }
    __syncthreads();

    short8 af[4], bfr[4];
#pragma unroll
    for (int i = 0; i < 4; ++i)
      af[i] = *(const short8*)&lA[(wr + i * 16 + frow) * 32 + fk];
#pragma unroll
    for (int i = 0; i < 4; ++i)
      bfr[i] = *(const short8*)&lB[(wc + i * 16 + frow) * 32 + fk];
#pragma unroll
    for (int i = 0; i < 4; ++i)
#pragma unroll
      for (int j = 0; j < 4; ++j)
        acc[i][j] = __builtin_amdgcn_mfma_f32_16x16x32_bf16(af[i], bfr[j], acc[i][j], 0, 0, 0);
  }

  const int r0 = quad * 4;
#pragma unroll
  for (int i = 0; i < 4; ++i) {
#pragma unroll
    for (int r = 0; r < 4; ++r) {
      const size_t row = bm + wr + i * 16 + r0 + r;
#pragma unroll
      for (int j = 0; j < 4; ++j) {
        const size_t col = bn + wc + j * 16 + frow;
        if (OUT_BF16) ((ushort*)Cout)[row * N + col] = f2bf(acc[i][j][r]);
        else          ((float*)Cout)[row * N + col] = acc[i][j][r];
      }
    }
  }
}

// ---------------------------------------------------------------------------
// Per-head LayerNorm + partial NeoX RoPE + split — VECTORIZED (v2).
// One wave = 8 slots (512 elems, short8 = 16B/lane coalesced); LN reduce =
// 3 shfl_xor within 8-lane groups; inv_freq = compile-time table; trig =
// __cosf/__sinf (hw v_cos_f32, err ~1e-3 << 0.069 threshold).
// Layout: row = gw/6, sg = gw%6 (sg 0..3 = Q slots, 4 = K, 5 = V);
// lane: head hs = lane>>3, elems de = (lane&7)*8.
// Q -> (b,h,s,d); K -> (b,kv,s,d); V -> (b,kv,d,s) transposed for flash.
// ---------------------------------------------------------------------------
static __device__ __forceinline__ float invf_of(int j) {
  const float t[8] = {1.0f, 0.31622776601683794f, 0.1f, 0.031622776601683791f,
                      0.01f, 0.0031622776601683794f, 0.001f, 0.00031622776601683794f};
  return t[j];
}

__global__ __launch_bounds__(256)
void ln_rope_split(const ushort* __restrict__ qkv, const int* __restrict__ pos_ids,
                   const float* __restrict__ qw, const float* __restrict__ kw,
                   ushort* __restrict__ Q, ushort* __restrict__ Kk, ushort* __restrict__ Vt) {
  const int gw   = (blockIdx.x * 256 + threadIdx.x) >> 6;
  const int lane = threadIdx.x & 63;
  const int row  = gw / 6;
  const int sg   = gw - row * 6;           // 0..3 Q, 4 K, 5 V
  const int b = row >> 11, s = row & 2047;
  const int hs = lane >> 3;                // head within the 8-slot group
  const int de = (lane & 7) * 8;           // elem start within head
  const int slot = sg * 8 + hs;

  const ushort8 xv = *(const ushort8*)&qkv[(size_t)row * QKV_N + sg * 512 + lane * 8];
  float x[8];
#pragma unroll
  for (int j = 0; j < 8; ++j) x[j] = bf2f(xv[j]);

  if (sg == 5) {                           // V: passthrough, transposed store
#pragma unroll
    for (int j = 0; j < 8; ++j)
      Vt[(((size_t)b * NKV + hs) * HD + de + j) * S_LEN + s] = f2bf(x[j]);
    return;
  }

  float s1 = 0.f, s2 = 0.f;
#pragma unroll
  for (int j = 0; j < 8; ++j) { s1 += x[j]; s2 += x[j] * x[j]; }
  s1 += __shfl_xor(s1, 1); s2 += __shfl_xor(s2, 1);
  s1 += __shfl_xor(s1, 2); s2 += __shfl_xor(s2, 2);
  s1 += __shfl_xor(s1, 4); s2 += __shfl_xor(s2, 4);
  const float mu  = s1 * 0.015625f;
  const float var = s2 * 0.015625f - mu * mu;
  const float rs  = rsqrtf(var + 1e-5f);

  const float* wb = (sg < 4) ? &qw[slot * 64 + de] : &kw[hs * 64 + de];
  float y[8];
#pragma unroll
  for (int j = 0; j < 8; ++j) y[j] = (x[j] - mu) * rs * wb[j];

  // RoPE on d<16: lane (lane&7)==0 holds x1 (d=j), ==1 holds x2 (d=8+j)
  const int lp = lane & 7;
  const float pos = (float)pos_ids[row];
  float yp[8];
#pragma unroll
  for (int j = 0; j < 8; ++j) yp[j] = __shfl_xor(y[j], 1);
  if (lp < 2) {
#pragma unroll
    for (int j = 0; j < 8; ++j) {
      const float fr = pos * invf_of(j);
      const float c = __cosf(fr), sn = __sinf(fr);
      y[j] = (lp == 0) ? (y[j] * c - yp[j] * sn) : (y[j] * c + yp[j] * sn);
    }
  }

  ushort8 o;
#pragma unroll
  for (int j = 0; j < 8; ++j) o[j] = f2bf(y[j]);
  if (sg < 4)
    *(ushort8*)&Q[(((size_t)b * NH + slot) * S_LEN + s) * HD + de] = o;
  else
    *(ushort8*)&Kk[(((size_t)b * NKV + hs) * S_LEN + s) * HD + de] = o;
}

// ---------------------------------------------------------------------------
// Causal GQA flash attention, FIXED-CAP softmax (no online rescaling):
// LayerNorm bounds |q|,|k| <= 8 -> s = q.k/8 in [-8.1,8.1]; p = exp(s-9)
// cannot overflow; softmax shift-invariance makes it exact.
//
// v9 = v8 with the P regroup bpermutes ELIMINATED via k-permutation.
// v8's LDS-pipe accounting: 8 ds_read_b128 + 16 ds_bpermute ~= 190cy/body
// vs 78cy MFMA -> LDS pipe was ~41us of the 73us kernel. MFMA contracts
// over operand POSITIONS, so any k-permutation applied consistently to A
// and B is exact. After cvt_pk, lane (frow,quad) natively holds
// P[frow][4q+j] (st00) and P[frow][16+4q+j] (st01) -> sigma(q,j) =
// {4q+j, 16+4q+j}; V read at matching offsets: two ds_read_b64 per
// d-block at row*32+4q and row*32+16+4q. A-fragment = 4 cvt_pk, zero
// shuffles. DS ops/body 24 -> 12.
//  * block = 4 waves = GQA group of one (b,kvh) at one qt strip; K+V
//    staged once via global_load_lds; m97 2-phase loop; K XOR-swizzled
//    both-sides; swapped QK^T; diagonal-only masking; folded exp.
// ---------------------------------------------------------------------------
#define EXPC1 0.180336880111f   // 0.125 * log2(e)
#define EXPC2 -12.9842553680f   // -9 * log2(e)

static __device__ __forceinline__ float expfast(float x) {
  float e;
  asm("v_exp_f32 %0, %1" : "=v"(e) : "v"(x));
  return e;
}

static __device__ __forceinline__ int cvtpk(float lo, float hi) {
  int w;
  asm("v_cvt_pk_bf16_f32 %0, %1, %2" : "=v"(w) : "v"(lo), "v"(hi));
  return w;
}

// Stage K tile rows jj..jj+31 (pre-swizzled source) and V tile cols jj..jj+31.
#define STAGE(BF, TI)                                                          \
  {                                                                            \
    const int jjs = (TI) * 32;                                                 \
    const ushort* gk = Kb + (size_t)(jjs + krow) * HD + kcol;                  \
    __builtin_amdgcn_global_load_lds(                                          \
        (const __attribute__((address_space(1))) void*)gk,                     \
        (__attribute__((address_space(3))) void*)&lK[BF][wchunk], 16, 0, 0);   \
    const ushort* gv = Vb + (size_t)vrow * S_LEN + jjs + vcol;                 \
    __builtin_amdgcn_global_load_lds(                                          \
        (const __attribute__((address_space(1))) void*)gv,                     \
        (__attribute__((address_space(3))) void*)&lV[BF][wchunk], 16, 0, 0);   \
  }

#define FA_BODY(BF, TI, MASKED)                                                \
  {                                                                            \
    const int jj = (TI) * 32;                                                  \
    const ushort* kb = &lK[BF][0];                                             \
    const ushort* vb = &lV[BF][0];                                             \
    const short8 kc0 = *(const short8*)&kb[frow * 64 + ksw0];                  \
    const short8 kc1 = *(const short8*)&kb[frow * 64 + (ksw0 ^ 32)];           \
    const short8 kc2 = *(const short8*)&kb[(16 + frow) * 64 + ksw0];           \
    const short8 kc3 = *(const short8*)&kb[(16 + frow) * 64 + (ksw0 ^ 32)];    \
    const floatx4 z = {};                                                      \
    floatx4 st00 = __builtin_amdgcn_mfma_f32_16x16x32_bf16(kc0, q00, z, 0, 0, 0); \
    st00 = __builtin_amdgcn_mfma_f32_16x16x32_bf16(kc1, q01, st00, 0, 0, 0);   \
    floatx4 st01 = __builtin_amdgcn_mfma_f32_16x16x32_bf16(kc2, q00, z, 0, 0, 0); \
    st01 = __builtin_amdgcn_mfma_f32_16x16x32_bf16(kc3, q01, st01, 0, 0, 0);   \
    floatx4 st10 = __builtin_amdgcn_mfma_f32_16x16x32_bf16(kc0, q10, z, 0, 0, 0); \
    st10 = __builtin_amdgcn_mfma_f32_16x16x32_bf16(kc1, q11, st10, 0, 0, 0);   \
    floatx4 st11 = __builtin_amdgcn_mfma_f32_16x16x32_bf16(kc2, q10, z, 0, 0, 0); \
    st11 = __builtin_amdgcn_mfma_f32_16x16x32_bf16(kc3, q11, st11, 0, 0, 0);   \
    union { long l[2]; short8 s; } uv0, uv1, uv2, uv3;                         \
    uv0.l[0] = *(const long*)&vb[( 0 + frow) * 32 + (quad << 2)];              \
    uv0.l[1] = *(const long*)&vb[( 0 + frow) * 32 + 16 + (quad << 2)];         \
    uv1.l[0] = *(const long*)&vb[(16 + frow) * 32 + (quad << 2)];              \
    uv1.l[1] = *(const long*)&vb[(16 + frow) * 32 + 16 + (quad << 2)];         \
    uv2.l[0] = *(const long*)&vb[(32 + frow) * 32 + (quad << 2)];              \
    uv2.l[1] = *(const long*)&vb[(32 + frow) * 32 + 16 + (quad << 2)];         \
    uv3.l[0] = *(const long*)&vb[(48 + frow) * 32 + (quad << 2)];              \
    uv3.l[1] = *(const long*)&vb[(48 + frow) * 32 + 16 + (quad << 2)];         \
    floatx4 p00, p01, p10, p11;                                                \
    _Pragma("unroll")                                                          \
    for (int r = 0; r < 4; ++r) {                                              \
      const float e00 = expfast(fmaf(st00[r], EXPC1, EXPC2));                  \
      const float e01 = expfast(fmaf(st01[r], EXPC1, EXPC2));                  \
      const float e10 = expfast(fmaf(st10[r], EXPC1, EXPC2));                  \
      const float e11 = expfast(fmaf(st11[r], EXPC1, EXPC2));                  \
      if (MASKED) {                                                            \
        const int kg0 = jj + quad * 4 + r;                                     \
        const int kg1 = kg0 + 16;                                              \
        p00[r] = (kg0 <= qm + frow)      ? e00 : 0.0f;                         \
        p01[r] = (kg1 <= qm + frow)      ? e01 : 0.0f;                         \
        p10[r] = (kg0 <= qm + 16 + frow) ? e10 : 0.0f;                         \
        p11[r] = (kg1 <= qm + 16 + frow) ? e11 : 0.0f;                         \
      } else {                                                                 \
        p00[r] = e00; p01[r] = e01; p10[r] = e10; p11[r] = e11;                \
      }                                                                        \
      lp0 += p00[r] + p01[r];                                                  \
      lp1 += p10[r] + p11[r];                                                  \
    }                                                                          \
    union { int i[4]; short8 s; } up0, up1;                                    \
    up0.i[0] = cvtpk(p00[0], p00[1]); up0.i[1] = cvtpk(p00[2], p00[3]);        \
    up0.i[2] = cvtpk(p01[0], p01[1]); up0.i[3] = cvtpk(p01[2], p01[3]);        \
    up1.i[0] = cvtpk(p10[0], p10[1]); up1.i[1] = cvtpk(p10[2], p10[3]);        \
    up1.i[2] = cvtpk(p11[0], p11[1]); up1.i[3] = cvtpk(p11[2], p11[3]);        \
    o00 = __builtin_amdgcn_mfma_f32_16x16x32_bf16(up0.s, uv0.s, o00, 0, 0, 0); \
    o01 = __builtin_amdgcn_mfma_f32_16x16x32_bf16(up0.s, uv1.s, o01, 0, 0, 0); \
    o02 = __builtin_amdgcn_mfma_f32_16x16x32_bf16(up0.s, uv2.s, o02, 0, 0, 0); \
    o03 = __builtin_amdgcn_mfma_f32_16x16x32_bf16(up0.s, uv3.s, o03, 0, 0, 0); \
    o10 = __builtin_amdgcn_mfma_f32_16x16x32_bf16(up1.s, uv0.s, o10, 0, 0, 0); \
    o11 = __builtin_amdgcn_mfma_f32_16x16x32_bf16(up1.s, uv1.s, o11, 0, 0, 0); \
    o12 = __builtin_amdgcn_mfma_f32_16x16x32_bf16(up1.s, uv2.s, o12, 0, 0, 0); \
    o13 = __builtin_amdgcn_mfma_f32_16x16x32_bf16(up1.s, uv3.s, o13, 0, 0, 0); \
  }

__global__ __launch_bounds__(256, 2)
void flash_attn(const ushort* __restrict__ Q, const ushort* __restrict__ Kk,
                const ushort* __restrict__ Vt, ushort* __restrict__ O) {
  __shared__ ushort lK[2][2048];   // [buf][32 rows x 64 d], K-swizzled
  __shared__ ushort lV[2][2048];   // [buf][64 d x 32 s], linear
  const int tid  = threadIdx.x;
  const int wave = tid >> 6, lane = tid & 63;
  const int bb  = blockIdx.x;
  const int xcd = bb & 7;
  const int j   = bb >> 3;                 // 0..127 per XCD
  const int qt  = 63 - (j >> 1);           // LPT: heavy strips dispatch first
  const int pr  = xcd * 2 + (j & 1);       // (b,kvh) pair; 2 kv-heads per XCD
  const int b   = pr >> 3, kvh = pr & 7;
  const int h   = kvh * 4 + wave;          // wave = q-head within GQA group
  const int qm  = qt * 32;
  const int frow = lane & 15, quad = lane >> 4, fk = quad * 8;

  // staging source coords (pre-swizzled K, linear V)
  const int krow = tid >> 3;
  const int kcol = (((tid & 7) ^ (krow & 7)) << 3);
  const int vrow = tid >> 2;
  const int vcol = ((tid & 3) << 3);
  const int wchunk = (tid >> 6) * 512;     // wave-uniform LDS chunk (elems)
  const int ksw0 = ((quad ^ (frow & 7)) << 3);

  const ushort* Qb = Q  + (((size_t)b * NH  + h)   * S_LEN + qm) * HD;
  const ushort* Kb = Kk + ((size_t)b * NKV + kvh)  * S_LEN * HD;
  const ushort* Vb = Vt + ((size_t)b * NKV + kvh)  * HD * S_LEN;

  const short8 q00 = *(const short8*)&Qb[frow * HD + fk];
  const short8 q01 = *(const short8*)&Qb[frow * HD + 32 + fk];
  const short8 q10 = *(const short8*)&Qb[(16 + frow) * HD + fk];
  const short8 q11 = *(const short8*)&Qb[(16 + frow) * HD + 32 + fk];

  floatx4 o00 = {}, o01 = {}, o02 = {}, o03 = {};
  floatx4 o10 = {}, o11 = {}, o12 = {}, o13 = {};
  float lp0 = 0.f, lp1 = 0.f;              // per-lane denom partial (q = frow)

  const int T = qt + 1;                    // tiles; last one is the diagonal

  STAGE(0, 0);
  __syncthreads();
  int buf = 0;
  for (int t = 0; t < T - 1; ++t) {
    STAGE(buf ^ 1, t + 1);
    FA_BODY(buf, t, 0);
    __syncthreads();
    buf ^= 1;
  }
  FA_BODY(buf, T - 1, 1);                  // masked diagonal tile

  // denom: sum across quads (k-direction), then transpose to O-row layout
  lp0 += __shfl_xor(lp0, 16); lp0 += __shfl_xor(lp0, 32);
  lp1 += __shfl_xor(lp1, 16); lp1 += __shfl_xor(lp1, 32);
  float lpq0[4], lpq1[4];
#pragma unroll
  for (int r = 0; r < 4; ++r) {
    lpq0[r] = __shfl(lp0, quad * 4 + r);
    lpq1[r] = __shfl(lp1, quad * 4 + r);
  }

  const size_t obase = ((size_t)b * S_LEN + qm) * HID + (size_t)h * HD;
#pragma unroll
  for (int r = 0; r < 4; ++r) {
    const float i0 = 1.0f / lpq0[r];
    const float i1 = 1.0f / lpq1[r];
    const size_t r0 = obase + (size_t)(quad * 4 + r) * HID;
    const size_t r1 = obase + (size_t)(16 + quad * 4 + r) * HID;
    O[r0 +  0 + frow] = f2bf(o00[r] * i0);
    O[r0 + 16 + frow] = f2bf(o01[r] * i0);
    O[r0 + 32 + frow] = f2bf(o02[r] * i0);
    O[r0 + 48 + frow] = f2bf(o03[r] * i0);
    O[r1 +  0 + frow] = f2bf(o10[r] * i1);
    O[r1 + 16 + frow] = f2bf(o11[r] * i1);
    O[r1 + 32 + frow] = f2bf(o12[r] * i1);
    O[r1 + 48 + frow] = f2bf(o13[r] * i1);
  }
}

// ---------------------------------------------------------------------------
// Workspace layout — 60 MiB:
//   R0 @ 0        (16 MiB): hb (hidden bf16) -> Q  (after gemm1)
//   R1 @ 16 MiB   (12 MiB): wq (w_qkv bf16)  -> wo (after gemm1)
//   R2 @ 28 MiB   (24 MiB): qkv              -> O  (after ln_rope)
//   R3 @ 52 MiB   ( 4 MiB): K
//   R4 @ 56 MiB   ( 4 MiB): Vt
// Output: fp32, written directly by gemm_nt<false>.
// ---------------------------------------------------------------------------
extern "C" void kernel_launch(void* const* d_in, const int* in_sizes, int n_in,
                              void* d_out, int out_size, void* d_ws, size_t ws_size,
                              hipStream_t stream) {
  (void)in_sizes; (void)n_in; (void)out_size; (void)ws_size;
  const int*   pos    = (const int*)d_in[0];
  const float* hidden = (const float*)d_in[1];
  const float* w_qkv  = (const float*)d_in[2];
  const float* q_ln_w = (const float*)d_in[3];
  const float* k_ln_w = (const float*)d_in[4];
  const float* w_o    = (const float*)d_in[5];

  char* ws = (char*)d_ws;
  ushort* hb  = (ushort*)(ws);
  ushort* Q   = (ushort*)(ws);                   // reuse R0
  ushort* wq  = (ushort*)(ws + 16777216);
  ushort* wo  = (ushort*)(ws + 16777216);        // reuse R1
  ushort* qkv = (ushort*)(ws + 29360128);
  ushort* O   = (ushort*)(ws + 29360128);        // reuse R2
  ushort* Kk  = (ushort*)(ws + 54525952);
  ushort* Vt  = (ushort*)(ws + 58720256);

  cvt_f32_bf16<<<dim3(4096), 256, 0, stream>>>(hidden, hb, 8388608 / 8);
  cvt_f32_bf16<<<dim3(3072), 256, 0, stream>>>(w_qkv, wq, 6291456 / 8);
  gemm_nt<true><<<dim3(QKV_N / 128, ROWS / 128), 256, 0, stream>>>(
      hb, wq, qkv, ROWS, QKV_N, HID);
  ln_rope_split<<<dim3(ROWS * 6 / 4), 256, 0, stream>>>(
      qkv, pos, q_ln_w, k_ln_w, Q, Kk, Vt);
  cvt_f32_bf16<<<dim3(2048), 256, 0, stream>>>(w_o, wo, 4194304 / 8);
  flash_attn<<<dim3(1024), 256, 0, stream>>>(Q, Kk, Vt, O);
  gemm_nt<false><<<dim3(HID / 128, ROWS / 128), 256, 0, stream>>>(
      O, wo, d_out, ROWS, HID, HID);
}